// Round 5
// baseline (197.173 us; speedup 1.0000x reference)
//
#include <hip/hip_runtime.h>
#include <hip/hip_fp16.h>

#define BATCH 4096
#define HH 32
#define WW 32
#define KPROP 20
#define NACT 4
#define DIN 3072   // H*W*3
#define DPHI 2048  // 2*H*W
#define HWC 1024   // H*W
#define KC 1024    // compacted K (walls only)

typedef _Float16 h8_t __attribute__((ext_vector_type(8)));
typedef _Float16 h4_t __attribute__((ext_vector_type(4)));
typedef float f32x4 __attribute__((ext_vector_type(4)));

__device__ inline float sigmoidf(float x) { return 1.0f / (1.0f + __expf(-x)); }

// DPP lane-shift helpers: 16-lane DPP rows; bound_ctrl=1 -> 0 at row edges.
__device__ inline float dpp_shr1(float x) {  // lane i <- lane i-1 (0 at i%16==0)
    return __int_as_float(__builtin_amdgcn_update_dpp(
        0, __float_as_int(x), 0x111, 0xF, 0xF, true));
}
__device__ inline float dpp_shl1(float x) {  // lane i <- lane i+1 (0 at i%16==15)
    return __int_as_float(__builtin_amdgcn_update_dpp(
        0, __float_as_int(x), 0x101, 0xF, 0xF, true));
}

// ------- P: fused prep. blocks [0,4096): compact walls + agent/goal idx.
//          blocks [4096,6144): Phi_w -> PwT (transposed f16 walls) + Pag (f16 rows). -------
__global__ __launch_bounds__(256) void prep_fused_kernel(
    const float* __restrict__ obs,    // (4096, 3072)
    const float* __restrict__ Phi_w,  // (3072, 2048)
    _Float16* __restrict__ W16,       // (4096, 1024)
    _Float16* __restrict__ PwT,       // (2048, 1024): PwT[n][c] = Phi_w[3c][n]
    _Float16* __restrict__ Pag,       // (2, 1024, 2048)
    int* __restrict__ aidx, int* __restrict__ gidx)
{
    __shared__ float tile[32][33];
    if (blockIdx.x < BATCH) {
        const int t = blockIdx.x * 256 + threadIdx.x;
        const int b = t >> 8;
        const int c0 = (t & 255) * 4;
        const float* src = obs + (size_t)b * DIN + 3 * c0;
        const float4 f0 = *(const float4*)(src);
        const float4 f1 = *(const float4*)(src + 4);
        const float4 f2 = *(const float4*)(src + 8);
        h4_t w;
        w[0] = (_Float16)f0.x; w[1] = (_Float16)f0.w;
        w[2] = (_Float16)f1.z; w[3] = (_Float16)f2.y;
        *(h4_t*)(W16 + (size_t)b * KC + c0) = w;
        if (f0.y > 0.5f) aidx[b] = c0;
        if (f1.x > 0.5f) aidx[b] = c0 + 1;
        if (f1.w > 0.5f) aidx[b] = c0 + 2;
        if (f2.z > 0.5f) aidx[b] = c0 + 3;
        if (f0.z > 0.5f) gidx[b] = c0;
        if (f1.y > 0.5f) gidx[b] = c0 + 1;
        if (f2.x > 0.5f) gidx[b] = c0 + 2;
        if (f2.w > 0.5f) gidx[b] = c0 + 3;
    } else {
        const int bid = blockIdx.x - BATCH;     // 0..2047
        const int ni = bid & 63;                // n tile
        const int ci = bid >> 6;                // c tile
        const int tx = threadIdx.x & 31;
        const int ty = threadIdx.x >> 5;        // 0..7
        #pragma unroll
        for (int s = 0; s < 4; s++) {
            const int r = ty + 8 * s;
            const int c = ci * 32 + r;
            const int n = ni * 32 + tx;
            tile[r][tx] = Phi_w[(size_t)(3 * c) * DPHI + n];
            Pag[(size_t)c * DPHI + n]         = (_Float16)Phi_w[(size_t)(3 * c + 1) * DPHI + n];
            Pag[(size_t)(HWC + c) * DPHI + n] = (_Float16)Phi_w[(size_t)(3 * c + 2) * DPHI + n];
        }
        __syncthreads();
        #pragma unroll
        for (int s = 0; s < 4; s++) {
            const int r = ty + 8 * s;
            PwT[(size_t)(ni * 32 + r) * KC + ci * 32 + tx] = (_Float16)tile[tx][r];
        }
    }
}

// ---------------- GEMM: pre = W16 @ PwT^T + bias, f16 out ----------------
// LDS-free, barrier-free: both operands are in MFMA fragment layout in global
// memory (K-major / N-major), so each wave global_load_dwordx4's its fragments
// straight into VGPRs. 64x64 per wave, 4 waves/block (block = 64x256), register
// double-buffer gives each load a full iteration of latency distance.
// Reuse: registers (16 MFMA / 8 loads) + L1 (4 waves share A addrs) + L2 (12 MB).
__global__ __launch_bounds__(256) void gemm_pre_kernel(
    const _Float16* __restrict__ A,    // (4096, 1024) K-major
    const _Float16* __restrict__ Bt,   // (2048, 1024) N-major
    const float* __restrict__ bias,    // (2048,)
    _Float16* __restrict__ pre)        // (4096, 2048)
{
    const int tid  = threadIdx.x;
    const int lane = tid & 63;
    const int wid  = tid >> 6;
    const int m0 = blockIdx.y * 64;
    const int n0 = blockIdx.x * 256 + wid * 64;
    const int lm = lane & 15;
    const int kq = lane >> 4;

    // lane's fragment base pointers (A-frag: row lm, k-octet kq; B-frag: col lm)
    const _Float16* Ap = A  + (size_t)(m0 + lm) * KC + kq * 8;
    const _Float16* Bp = Bt + (size_t)(n0 + lm) * KC + kq * 8;

    f32x4 acc[4][4] = {};
    h8_t a_cur[4], b_cur[4], a_nxt[4], b_nxt[4];

    #pragma unroll
    for (int i = 0; i < 4; i++) {
        a_cur[i] = *(const h8_t*)(Ap + (size_t)i * 16 * KC);
        b_cur[i] = *(const h8_t*)(Bp + (size_t)i * 16 * KC);
    }

    for (int k0 = 32; k0 <= KC; k0 += 32) {
        if (k0 < KC) {
            #pragma unroll
            for (int i = 0; i < 4; i++) {
                a_nxt[i] = *(const h8_t*)(Ap + (size_t)i * 16 * KC + k0);
                b_nxt[i] = *(const h8_t*)(Bp + (size_t)i * 16 * KC + k0);
            }
        }
        #pragma unroll
        for (int mt = 0; mt < 4; mt++)
            #pragma unroll
            for (int nt = 0; nt < 4; nt++)
                acc[mt][nt] = __builtin_amdgcn_mfma_f32_16x16x32_f16(
                    a_cur[mt], b_cur[nt], acc[mt][nt], 0, 0, 0);
        #pragma unroll
        for (int i = 0; i < 4; i++) { a_cur[i] = a_nxt[i]; b_cur[i] = b_nxt[i]; }
    }

    #pragma unroll
    for (int nt = 0; nt < 4; nt++) {
        const int col = n0 + nt * 16 + lm;
        const float bcol = bias[col];
        #pragma unroll
        for (int mt = 0; mt < 4; mt++) {
            #pragma unroll
            for (int r = 0; r < 4; r++) {
                const int row = m0 + mt * 16 + kq * 4 + r;
                pre[(size_t)row * DPHI + col] = (_Float16)(acc[mt][nt][r] + bcol);
            }
        }
    }
}

// ---------------- B: sigmoid + 20-step vprop in registers + head MLP ----------------
__global__ __launch_bounds__(256, 4) void vprop_head_kernel(
    const _Float16* __restrict__ pre,  // (4096, 2048)
    const _Float16* __restrict__ Pag,  // (2, 1024, 2048)
    const float* __restrict__ obs,     // (4096, 3072)
    const int* __restrict__ aidx,
    const int* __restrict__ gidx,
    const float* __restrict__ L1w,     // (36,16)
    const float* __restrict__ L1b,
    const float* __restrict__ L2w,     // (16,4)
    const float* __restrict__ L2b,
    float* __restrict__ out)           // (4096, 4)
{
    __shared__ __align__(16) float Vg[4][HWC];
    __shared__ float sel[4][36], hbuf[4][16];

    const int tid  = threadIdx.x;
    const int w    = tid >> 6;
    const int lane = tid & 63;
    const int b    = blockIdx.x * 4 + w;
    const int bi   = lane & 15;
    const int bj   = lane >> 4;
    const int ai = aidx[b];
    const int gi = gidx[b];

    const _Float16* pb = pre + (size_t)b * DPHI;
    const _Float16* ra = Pag + (size_t)ai * DPHI;
    const _Float16* rg = Pag + (size_t)(HWC + gi) * DPHI;

    float v[2][8], p[2][8], a[2][8];
    #pragma unroll
    for (int r = 0; r < 2; r++) {
        const int off = 64 * (2 * bi + r) + 16 * bj;
        const h8_t ph0 = *(const h8_t*)(pb + off), ph1 = *(const h8_t*)(pb + off + 8);
        const h8_t pa0 = *(const h8_t*)(ra + off), pa1 = *(const h8_t*)(ra + off + 8);
        const h8_t pg0 = *(const h8_t*)(rg + off), pg1 = *(const h8_t*)(rg + off + 8);
        #pragma unroll
        for (int c = 0; c < 4; c++) {
            const float rv = sigmoidf((float)ph0[2*c]   + (float)pa0[2*c]   + (float)pg0[2*c]);
            const float pv = sigmoidf((float)ph0[2*c+1] + (float)pa0[2*c+1] + (float)pg0[2*c+1]);
            v[r][c] = rv; p[r][c] = pv; a[r][c] = rv * (1.0f - pv);
            const float rv2 = sigmoidf((float)ph1[2*c]   + (float)pa1[2*c]   + (float)pg1[2*c]);
            const float pv2 = sigmoidf((float)ph1[2*c+1] + (float)pa1[2*c+1] + (float)pg1[2*c+1]);
            v[r][c+4] = rv2; p[r][c+4] = pv2; a[r][c+4] = rv2 * (1.0f - pv2);
        }
    }

    for (int it = 0; it < KPROP; it++) {
        float uh[8], dh[8], lh[2], rh[2];
        #pragma unroll
        for (int c = 0; c < 8; c++) {
            uh[c] = dpp_shr1(v[1][c]);
            dh[c] = dpp_shl1(v[0][c]);
        }
        #pragma unroll
        for (int r = 0; r < 2; r++) {
            lh[r] = __shfl(v[r][7], lane - 16);
            rh[r] = __shfl(v[r][0], lane + 16);
            if (bj == 0) lh[r] = 0.0f;
            if (bj == 3) rh[r] = 0.0f;
        }
        float nb[2][8];
        #pragma unroll
        for (int c = 0; c < 8; c++) {
            const float lf0 = (c == 0) ? lh[0] : v[0][c-1];
            const float rt0 = (c == 7) ? rh[0] : v[0][c+1];
            const float lf1 = (c == 0) ? lh[1] : v[1][c-1];
            const float rt1 = (c == 7) ? rh[1] : v[1][c+1];
            nb[0][c] = fmaxf(fmaxf(uh[c], v[1][c]), fmaxf(lf0, rt0));
            nb[1][c] = fmaxf(fmaxf(v[0][c], dh[c]), fmaxf(lf1, rt1));
        }
        #pragma unroll
        for (int r = 0; r < 2; r++)
            #pragma unroll
            for (int c = 0; c < 8; c++)
                v[r][c] = fmaxf(v[r][c], fmaf(p[r][c], nb[r][c], a[r][c]));
    }

    #pragma unroll
    for (int r = 0; r < 2; r++) {
        float4 lo, hi;
        lo.x = v[r][0]; lo.y = v[r][1]; lo.z = v[r][2]; lo.w = v[r][3];
        hi.x = v[r][4]; hi.y = v[r][5]; hi.z = v[r][6]; hi.w = v[r][7];
        const int base = (2 * bi + r) * 32 + 8 * bj;
        *(float4*)&Vg[w][base]     = lo;
        *(float4*)&Vg[w][base + 4] = hi;
    }
    __syncthreads();

    const int pi = ai >> 5, pj = ai & 31;
    if (lane < 36) {
        const int cell = lane >> 2;
        const int ch = lane & 3;
        const int di = pi + cell / 3 - 1;
        const int dj = pj + cell % 3 - 1;
        float vv = 0.0f;
        if (di >= 0 && di < HH && dj >= 0 && dj < WW) {
            const int c = di * WW + dj;
            vv = (ch < 3) ? obs[(size_t)b * DIN + 3 * c + ch] : Vg[w][c];
        }
        sel[w][lane] = vv;
    }
    __syncthreads();

    if (lane < 16) {
        float h = L1b[lane];
        #pragma unroll
        for (int k = 0; k < 36; k++) h += sel[w][k] * L1w[k * 16 + lane];
        hbuf[w][lane] = fmaxf(h, 0.0f);
    }
    __syncthreads();

    if (lane < 4) {
        float o = L2b[lane];
        #pragma unroll
        for (int t = 0; t < 16; t++) o += hbuf[w][t] * L2w[t * 4 + lane];
        out[(size_t)b * NACT + lane] = o;
    }
}

extern "C" void kernel_launch(void* const* d_in, const int* in_sizes, int n_in,
                              void* d_out, int out_size, void* d_ws, size_t ws_size,
                              hipStream_t stream) {
    const float* obs   = (const float*)d_in[0];
    const float* Phi_w = (const float*)d_in[1];
    const float* Phi_b = (const float*)d_in[2];
    const float* L1w   = (const float*)d_in[3];
    const float* L1b   = (const float*)d_in[4];
    const float* L2w   = (const float*)d_in[5];
    const float* L2b   = (const float*)d_in[6];
    float* out = (float*)d_out;

    char* ws = (char*)d_ws;
    _Float16* pre = (_Float16*)ws;                  // 16,777,216 B
    _Float16* W16 = (_Float16*)(ws + 16777216);     //  8,388,608 B
    _Float16* PwT = (_Float16*)(ws + 25165824);     //  4,194,304 B
    _Float16* Pag = (_Float16*)(ws + 29360128);     //  8,388,608 B
    int* aidx = (int*)(ws + 37748736);              //     16,384 B
    int* gidx = aidx + BATCH;                       //     16,384 B

    prep_fused_kernel<<<BATCH + 2048, 256, 0, stream>>>(obs, Phi_w, W16, PwT, Pag, aidx, gidx);
    gemm_pre_kernel<<<dim3(DPHI / 256, BATCH / 64), 256, 0, stream>>>(W16, PwT, Phi_b, pre);
    vprop_head_kernel<<<BATCH / 4, 256, 0, stream>>>(pre, Pag, obs, aidx, gidx,
                                                     L1w, L1b, L2w, L2b, out);
}

// Round 6
// 163.892 us; speedup vs baseline: 1.2031x; 1.2031x over previous
//
#include <hip/hip_runtime.h>
#include <hip/hip_fp16.h>

#define BATCH 4096
#define HH 32
#define WW 32
#define KPROP 20
#define NACT 4
#define DIN 3072   // H*W*3
#define DPHI 2048  // 2*H*W
#define HWC 1024   // H*W
#define KC 1024    // compacted K (walls only)
#define TILE_ELEMS (16 * KC)   // one 16-row fragment-packed tile: [k/8][16][8]

typedef _Float16 h8_t __attribute__((ext_vector_type(8)));
typedef _Float16 h4_t __attribute__((ext_vector_type(4)));
typedef float f32x4 __attribute__((ext_vector_type(4)));

__device__ inline float sigmoidf(float x) { return 1.0f / (1.0f + __expf(-x)); }

// DPP lane-shift helpers: 16-lane DPP rows; bound_ctrl=1 -> 0 at row edges.
__device__ inline float dpp_shr1(float x) {  // lane i <- lane i-1 (0 at i%16==0)
    return __int_as_float(__builtin_amdgcn_update_dpp(
        0, __float_as_int(x), 0x111, 0xF, 0xF, true));
}
__device__ inline float dpp_shl1(float x) {  // lane i <- lane i+1 (0 at i%16==15)
    return __int_as_float(__builtin_amdgcn_update_dpp(
        0, __float_as_int(x), 0x101, 0xF, 0xF, true));
}

// Fragment-packed layout: P[t][ko][lm][j] with t=row/16, ko=k/8, lm=row%16, j=k%8.
// A wave's 16x32 fragment load (lane = kq*16+lm) is then *contiguous*:
//   elem offset = t*16384 + k0*16 + 8*lane.
__device__ inline size_t pack_off(int row, int k) {
    return (size_t)(row >> 4) * TILE_ELEMS + (k >> 3) * 128 + (row & 15) * 8 + (k & 7);
}

// ------- P: fused prep. blocks [0,4096): pack walls + agent/goal idx.
//          blocks [4096,6144): Phi_w -> B_pack (fragment-packed f16 walls) + Pag. -------
__global__ __launch_bounds__(256) void prep_fused_kernel(
    const float* __restrict__ obs,    // (4096, 3072)
    const float* __restrict__ Phi_w,  // (3072, 2048)
    _Float16* __restrict__ A_pack,    // (4096/16, 128, 16, 8)
    _Float16* __restrict__ B_pack,    // (2048/16, 128, 16, 8): element (n,c) = Phi_w[3c][n]
    _Float16* __restrict__ Pag,       // (2, 1024, 2048)
    int* __restrict__ aidx, int* __restrict__ gidx)
{
    if (blockIdx.x < BATCH) {
        const int t = blockIdx.x * 256 + threadIdx.x;
        const int b = t >> 8;
        const int c0 = (t & 255) * 4;
        const float* src = obs + (size_t)b * DIN + 3 * c0;
        const float4 f0 = *(const float4*)(src);
        const float4 f1 = *(const float4*)(src + 4);
        const float4 f2 = *(const float4*)(src + 8);
        h4_t w;
        w[0] = (_Float16)f0.x; w[1] = (_Float16)f0.w;
        w[2] = (_Float16)f1.z; w[3] = (_Float16)f2.y;
        *(h4_t*)(A_pack + pack_off(b, c0)) = w;   // c0 4-aligned: stays in one octet run
        if (f0.y > 0.5f) aidx[b] = c0;
        if (f1.x > 0.5f) aidx[b] = c0 + 1;
        if (f1.w > 0.5f) aidx[b] = c0 + 2;
        if (f2.z > 0.5f) aidx[b] = c0 + 3;
        if (f0.z > 0.5f) gidx[b] = c0;
        if (f1.y > 0.5f) gidx[b] = c0 + 1;
        if (f2.x > 0.5f) gidx[b] = c0 + 2;
        if (f2.w > 0.5f) gidx[b] = c0 + 3;
    } else {
        const int bid = blockIdx.x - BATCH;     // 0..2047
        const int ni = bid & 63;                // n tile (32 wide)
        const int ci = bid >> 6;                // c tile (32 wide)
        const int tx = threadIdx.x & 31;
        const int ty = threadIdx.x >> 5;        // 0..7
        #pragma unroll
        for (int s = 0; s < 4; s++) {
            const int r = ty + 8 * s;
            const int c = ci * 32 + r;
            const int n = ni * 32 + tx;
            const float w0 = Phi_w[(size_t)(3 * c) * DPHI + n];
            Pag[(size_t)c * DPHI + n]         = (_Float16)Phi_w[(size_t)(3 * c + 1) * DPHI + n];
            Pag[(size_t)(HWC + c) * DPHI + n] = (_Float16)Phi_w[(size_t)(3 * c + 2) * DPHI + n];
            B_pack[pack_off(n, c)] = (_Float16)w0;   // transpose via packed scatter
        }
    }
}

// ---------------- GEMM: pre = walls @ wallsW^T + bias, f16 out ----------------
// LDS-free, barrier-free. Operands fragment-packed -> each wave fragment load is
// 1 KB contiguous (elem offset = tile*16384 + k0*16 + 8*lane). Even/odd register
// buffers (no copies) let MFMA on one buffer proceed while the other buffer's 8
// loads stay in flight (partial-vmcnt pipeline). 64x64/wave, 4 waves/block.
__global__ __launch_bounds__(256) void gemm_pre_kernel(
    const _Float16* __restrict__ A_pack,  // (256, 16384)
    const _Float16* __restrict__ B_pack,  // (128, 16384)
    const float* __restrict__ bias,       // (2048,)
    _Float16* __restrict__ pre)           // (4096, 2048)
{
    const int tid  = threadIdx.x;
    const int lane = tid & 63;
    const int wid  = tid >> 6;
    const int m0 = blockIdx.y * 64;                 // 64 rows/block
    const int n0 = blockIdx.x * 256 + wid * 64;     // 64 cols/wave
    const int lm = lane & 15;
    const int kq = lane >> 4;

    const _Float16* Abase = A_pack + (size_t)(blockIdx.y * 4) * TILE_ELEMS + 8 * lane;
    const _Float16* Bbase = B_pack + (size_t)(blockIdx.x * 16 + wid * 4) * TILE_ELEMS + 8 * lane;

    f32x4 acc[4][4] = {};
    h8_t a0[4], b0[4], a1[4], b1[4];

    #pragma unroll
    for (int i = 0; i < 4; i++) {
        a0[i] = *(const h8_t*)(Abase + i * TILE_ELEMS);
        b0[i] = *(const h8_t*)(Bbase + i * TILE_ELEMS);
        a1[i] = *(const h8_t*)(Abase + i * TILE_ELEMS + 32 * 16);
        b1[i] = *(const h8_t*)(Bbase + i * TILE_ELEMS + 32 * 16);
    }

    for (int k0 = 0; k0 < KC; k0 += 64) {
        #pragma unroll
        for (int mt = 0; mt < 4; mt++)
            #pragma unroll
            for (int nt = 0; nt < 4; nt++)
                acc[mt][nt] = __builtin_amdgcn_mfma_f32_16x16x32_f16(
                    a0[mt], b0[nt], acc[mt][nt], 0, 0, 0);
        if (k0 + 64 < KC) {
            #pragma unroll
            for (int i = 0; i < 4; i++) {
                a0[i] = *(const h8_t*)(Abase + i * TILE_ELEMS + (k0 + 64) * 16);
                b0[i] = *(const h8_t*)(Bbase + i * TILE_ELEMS + (k0 + 64) * 16);
            }
        }
        #pragma unroll
        for (int mt = 0; mt < 4; mt++)
            #pragma unroll
            for (int nt = 0; nt < 4; nt++)
                acc[mt][nt] = __builtin_amdgcn_mfma_f32_16x16x32_f16(
                    a1[mt], b1[nt], acc[mt][nt], 0, 0, 0);
        if (k0 + 96 < KC) {
            #pragma unroll
            for (int i = 0; i < 4; i++) {
                a1[i] = *(const h8_t*)(Abase + i * TILE_ELEMS + (k0 + 96) * 16);
                b1[i] = *(const h8_t*)(Bbase + i * TILE_ELEMS + (k0 + 96) * 16);
            }
        }
    }

    #pragma unroll
    for (int nt = 0; nt < 4; nt++) {
        const int col = n0 + nt * 16 + lm;
        const float bcol = bias[col];
        #pragma unroll
        for (int mt = 0; mt < 4; mt++) {
            #pragma unroll
            for (int r = 0; r < 4; r++) {
                const int row = m0 + mt * 16 + kq * 4 + r;
                pre[(size_t)row * DPHI + col] = (_Float16)(acc[mt][nt][r] + bcol);
            }
        }
    }
}

// ---------------- B: sigmoid + 20-step vprop in registers + head MLP ----------------
__global__ __launch_bounds__(256, 4) void vprop_head_kernel(
    const _Float16* __restrict__ pre,  // (4096, 2048)
    const _Float16* __restrict__ Pag,  // (2, 1024, 2048)
    const float* __restrict__ obs,     // (4096, 3072)
    const int* __restrict__ aidx,
    const int* __restrict__ gidx,
    const float* __restrict__ L1w,     // (36,16)
    const float* __restrict__ L1b,
    const float* __restrict__ L2w,     // (16,4)
    const float* __restrict__ L2b,
    float* __restrict__ out)           // (4096, 4)
{
    __shared__ __align__(16) float Vg[4][HWC];
    __shared__ float sel[4][36], hbuf[4][16];

    const int tid  = threadIdx.x;
    const int w    = tid >> 6;
    const int lane = tid & 63;
    const int b    = blockIdx.x * 4 + w;
    const int bi   = lane & 15;
    const int bj   = lane >> 4;
    const int ai = aidx[b];
    const int gi = gidx[b];

    const _Float16* pb = pre + (size_t)b * DPHI;
    const _Float16* ra = Pag + (size_t)ai * DPHI;
    const _Float16* rg = Pag + (size_t)(HWC + gi) * DPHI;

    float v[2][8], p[2][8], a[2][8];
    #pragma unroll
    for (int r = 0; r < 2; r++) {
        const int off = 64 * (2 * bi + r) + 16 * bj;
        const h8_t ph0 = *(const h8_t*)(pb + off), ph1 = *(const h8_t*)(pb + off + 8);
        const h8_t pa0 = *(const h8_t*)(ra + off), pa1 = *(const h8_t*)(ra + off + 8);
        const h8_t pg0 = *(const h8_t*)(rg + off), pg1 = *(const h8_t*)(rg + off + 8);
        #pragma unroll
        for (int c = 0; c < 4; c++) {
            const float rv = sigmoidf((float)ph0[2*c]   + (float)pa0[2*c]   + (float)pg0[2*c]);
            const float pv = sigmoidf((float)ph0[2*c+1] + (float)pa0[2*c+1] + (float)pg0[2*c+1]);
            v[r][c] = rv; p[r][c] = pv; a[r][c] = rv * (1.0f - pv);
            const float rv2 = sigmoidf((float)ph1[2*c]   + (float)pa1[2*c]   + (float)pg1[2*c]);
            const float pv2 = sigmoidf((float)ph1[2*c+1] + (float)pa1[2*c+1] + (float)pg1[2*c+1]);
            v[r][c+4] = rv2; p[r][c+4] = pv2; a[r][c+4] = rv2 * (1.0f - pv2);
        }
    }

    for (int it = 0; it < KPROP; it++) {
        float uh[8], dh[8], lh[2], rh[2];
        #pragma unroll
        for (int c = 0; c < 8; c++) {
            uh[c] = dpp_shr1(v[1][c]);
            dh[c] = dpp_shl1(v[0][c]);
        }
        #pragma unroll
        for (int r = 0; r < 2; r++) {
            lh[r] = __shfl(v[r][7], lane - 16);
            rh[r] = __shfl(v[r][0], lane + 16);
            if (bj == 0) lh[r] = 0.0f;
            if (bj == 3) rh[r] = 0.0f;
        }
        float nb[2][8];
        #pragma unroll
        for (int c = 0; c < 8; c++) {
            const float lf0 = (c == 0) ? lh[0] : v[0][c-1];
            const float rt0 = (c == 7) ? rh[0] : v[0][c+1];
            const float lf1 = (c == 0) ? lh[1] : v[1][c-1];
            const float rt1 = (c == 7) ? rh[1] : v[1][c+1];
            nb[0][c] = fmaxf(fmaxf(uh[c], v[1][c]), fmaxf(lf0, rt0));
            nb[1][c] = fmaxf(fmaxf(v[0][c], dh[c]), fmaxf(lf1, rt1));
        }
        #pragma unroll
        for (int r = 0; r < 2; r++)
            #pragma unroll
            for (int c = 0; c < 8; c++)
                v[r][c] = fmaxf(v[r][c], fmaf(p[r][c], nb[r][c], a[r][c]));
    }

    #pragma unroll
    for (int r = 0; r < 2; r++) {
        float4 lo, hi;
        lo.x = v[r][0]; lo.y = v[r][1]; lo.z = v[r][2]; lo.w = v[r][3];
        hi.x = v[r][4]; hi.y = v[r][5]; hi.z = v[r][6]; hi.w = v[r][7];
        const int base = (2 * bi + r) * 32 + 8 * bj;
        *(float4*)&Vg[w][base]     = lo;
        *(float4*)&Vg[w][base + 4] = hi;
    }
    __syncthreads();

    const int pi = ai >> 5, pj = ai & 31;
    if (lane < 36) {
        const int cell = lane >> 2;
        const int ch = lane & 3;
        const int di = pi + cell / 3 - 1;
        const int dj = pj + cell % 3 - 1;
        float vv = 0.0f;
        if (di >= 0 && di < HH && dj >= 0 && dj < WW) {
            const int c = di * WW + dj;
            vv = (ch < 3) ? obs[(size_t)b * DIN + 3 * c + ch] : Vg[w][c];
        }
        sel[w][lane] = vv;
    }
    __syncthreads();

    if (lane < 16) {
        float h = L1b[lane];
        #pragma unroll
        for (int k = 0; k < 36; k++) h += sel[w][k] * L1w[k * 16 + lane];
        hbuf[w][lane] = fmaxf(h, 0.0f);
    }
    __syncthreads();

    if (lane < 4) {
        float o = L2b[lane];
        #pragma unroll
        for (int t = 0; t < 16; t++) o += hbuf[w][t] * L2w[t * 4 + lane];
        out[(size_t)b * NACT + lane] = o;
    }
}

extern "C" void kernel_launch(void* const* d_in, const int* in_sizes, int n_in,
                              void* d_out, int out_size, void* d_ws, size_t ws_size,
                              hipStream_t stream) {
    const float* obs   = (const float*)d_in[0];
    const float* Phi_w = (const float*)d_in[1];
    const float* Phi_b = (const float*)d_in[2];
    const float* L1w   = (const float*)d_in[3];
    const float* L1b   = (const float*)d_in[4];
    const float* L2w   = (const float*)d_in[5];
    const float* L2b   = (const float*)d_in[6];
    float* out = (float*)d_out;

    char* ws = (char*)d_ws;
    _Float16* pre    = (_Float16*)ws;                  // 16,777,216 B
    _Float16* A_pack = (_Float16*)(ws + 16777216);     //  8,388,608 B
    _Float16* B_pack = (_Float16*)(ws + 25165824);     //  4,194,304 B
    _Float16* Pag    = (_Float16*)(ws + 29360128);     //  8,388,608 B
    int* aidx = (int*)(ws + 37748736);                 //     16,384 B
    int* gidx = aidx + BATCH;                          //     16,384 B

    prep_fused_kernel<<<BATCH + 2048, 256, 0, stream>>>(obs, Phi_w, A_pack, B_pack, Pag, aidx, gidx);
    gemm_pre_kernel<<<dim3(DPHI / 256, BATCH / 64), 256, 0, stream>>>(A_pack, B_pack, Phi_b, pre);
    vprop_head_kernel<<<BATCH / 4, 256, 0, stream>>>(pre, Pag, obs, aidx, gidx,
                                                     L1w, L1b, L2w, L2b, out);
}